// Round 3
// baseline (690.871 us; speedup 1.0000x reference)
//
#include <hip/hip_runtime.h>
#include <hip/hip_bf16.h>

#define N_NODES 100000
#define N_EDGES 1600000

// ---------------- CSR build ----------------

__global__ void init_kernel(float* deg, int* cursor) {
    int i = blockIdx.x * 256 + threadIdx.x;
    if (i < N_NODES) { deg[i] = 1.0f; cursor[i] = 0; }
}

__global__ void count_kernel(const int* __restrict__ ei, const float* __restrict__ w,
                             float* deg, int* cursor) {
    int e = blockIdx.x * 256 + threadIdx.x;
    if (e < N_EDGES) {
        int c = ei[N_EDGES + e];
        atomicAdd(&deg[c], w[e]);
        atomicAdd(&cursor[c], 1);
    }
}

__global__ void dinv_kernel(float* deg) {
    int i = blockIdx.x * 256 + threadIdx.x;
    if (i < N_NODES) deg[i] = rsqrtf(deg[i]);
}

// per-block exclusive scan; off[i] = block-local exclusive, bsum[b] = block total
__global__ void scanA_kernel(const int* __restrict__ cnt, int* __restrict__ off, int* __restrict__ bsum) {
    __shared__ int s[1024];
    int t = threadIdx.x;
    int i = blockIdx.x * 1024 + t;
    int v = (i < N_NODES) ? cnt[i] : 0;
    s[t] = v; __syncthreads();
    #pragma unroll
    for (int d = 1; d < 1024; d <<= 1) {
        int x = (t >= d) ? s[t - d] : 0;
        __syncthreads();
        s[t] += x;
        __syncthreads();
    }
    if (i < N_NODES) off[i] = s[t] - v;
    if (t == 1023) bsum[blockIdx.x] = s[1023];
}

__global__ void scanB_kernel(int* bsum, int nb) {
    __shared__ int s[1024];
    int t = threadIdx.x;
    int v = (t < nb) ? bsum[t] : 0;
    s[t] = v; __syncthreads();
    #pragma unroll
    for (int d = 1; d < 1024; d <<= 1) {
        int x = (t >= d) ? s[t - d] : 0;
        __syncthreads();
        s[t] += x;
        __syncthreads();
    }
    if (t < nb) bsum[t] = s[t] - v;
}

__global__ void scanC_kernel(int* __restrict__ off, const int* __restrict__ bsum, int* __restrict__ cursor) {
    int i = blockIdx.x * 1024 + threadIdx.x;
    if (i < N_NODES) {
        int o = off[i] + bsum[blockIdx.x];
        off[i] = o;
        cursor[i] = o;
    }
    if (i == 0) off[N_NODES] = N_EDGES;
}

__global__ void fill_kernel(const int* __restrict__ ei, const float* __restrict__ w,
                            const float* __restrict__ dinv, int* cursor,
                            int* __restrict__ esrc, float* __restrict__ enrm) {
    int e = blockIdx.x * 256 + threadIdx.x;
    if (e < N_EDGES) {
        int r = ei[e];
        int c = ei[N_EDGES + e];
        int p = atomicAdd(&cursor[c], 1);
        esrc[p] = r;
        enrm[p] = dinv[r] * w[e] * dinv[c];
    }
}

// ---------------- GEMM1: XW = X @ W1   (100000x128 @ 128x128) ----------------

__global__ __launch_bounds__(256) void gemm1_kernel(const float* __restrict__ X,
                                                    const float* __restrict__ W,
                                                    float* __restrict__ XW) {
    __shared__ float sA[32][132];   // [k][m]
    __shared__ float sB[32][132];   // [k][n] (128 used)
    int t = threadIdx.x;
    int row0 = blockIdx.x * 128;
    int tc = t & 15, tr = t >> 4;
    int m0 = tr * 8, n0 = tc * 8;
    float acc[8][8] = {};
    for (int kt = 0; kt < 128; kt += 32) {
        // stage A (transpose to [k][m])
        #pragma unroll
        for (int q = 0; q < 4; ++q) {
            int g = t + q * 256;          // 0..1023
            int row = g >> 3;
            int c4 = g & 7;
            float4 v = make_float4(0.f, 0.f, 0.f, 0.f);
            int grow = row0 + row;
            if (grow < N_NODES) v = *(const float4*)(X + (size_t)grow * 128 + kt + c4 * 4);
            sA[c4 * 4 + 0][row] = v.x;
            sA[c4 * 4 + 1][row] = v.y;
            sA[c4 * 4 + 2][row] = v.z;
            sA[c4 * 4 + 3][row] = v.w;
        }
        // stage B
        #pragma unroll
        for (int q = 0; q < 4; ++q) {
            int g = t + q * 256;
            int k = g >> 5, n4 = g & 31;
            *(float4*)(&sB[k][n4 * 4]) = *(const float4*)(W + (kt + k) * 128 + n4 * 4);
        }
        __syncthreads();
        #pragma unroll
        for (int k = 0; k < 32; ++k) {
            float4 a0 = *(const float4*)(&sA[k][m0]);
            float4 a1 = *(const float4*)(&sA[k][m0 + 4]);
            float4 b0 = *(const float4*)(&sB[k][n0]);
            float4 b1v = *(const float4*)(&sB[k][n0 + 4]);
            float a[8] = {a0.x, a0.y, a0.z, a0.w, a1.x, a1.y, a1.z, a1.w};
            float b[8] = {b0.x, b0.y, b0.z, b0.w, b1v.x, b1v.y, b1v.z, b1v.w};
            #pragma unroll
            for (int j = 0; j < 8; ++j)
                #pragma unroll
                for (int i = 0; i < 8; ++i) acc[j][i] += a[j] * b[i];
        }
        __syncthreads();
    }
    #pragma unroll
    for (int j = 0; j < 8; ++j) {
        int grow = row0 + m0 + j;
        if (grow < N_NODES) {
            float4 v0 = {acc[j][0], acc[j][1], acc[j][2], acc[j][3]};
            float4 v1 = {acc[j][4], acc[j][5], acc[j][6], acc[j][7]};
            *(float4*)(XW + (size_t)grow * 128 + n0) = v0;
            *(float4*)(XW + (size_t)grow * 128 + n0 + 4) = v1;
        }
    }
}

// ---------------- Aggregation layer 1 (wave per node) + b1 + relu ----------------

__global__ __launch_bounds__(256) void agg1_kernel(const float* __restrict__ XW,
                                                   const int* __restrict__ off,
                                                   const int* __restrict__ esrc,
                                                   const float* __restrict__ enrm,
                                                   const float* __restrict__ dinv,
                                                   const float* __restrict__ b1,
                                                   float* __restrict__ H) {
    int n = blockIdx.x * 4 + (threadIdx.x >> 6);
    int l = threadIdx.x & 63;
    if (n >= N_NODES) return;
    float di = dinv[n];
    float self = di * di;
    float a0 = self * XW[(size_t)n * 128 + l];
    float a1 = self * XW[(size_t)n * 128 + 64 + l];
    int e0 = off[n], e1 = off[n + 1];
    for (int e = e0; e < e1; ++e) {
        int s = esrc[e];
        float w = enrm[e];
        a0 += w * XW[(size_t)s * 128 + l];
        a1 += w * XW[(size_t)s * 128 + 64 + l];
    }
    a0 += b1[l];
    a1 += b1[64 + l];
    H[(size_t)n * 128 + l] = fmaxf(a0, 0.f);
    H[(size_t)n * 128 + 64 + l] = fmaxf(a1, 0.f);
}

// ---------------- GEMM2: HW = H @ W2   (100000x128 @ 128x40) ----------------

__global__ __launch_bounds__(256) void gemm2_kernel(const float* __restrict__ H,
                                                    const float* __restrict__ W2,
                                                    float* __restrict__ HW) {
    __shared__ float sA[64][132];  // [m][k]
    __shared__ float sB[40][132];  // [c][k]
    int t = threadIdx.x;
    int row0 = blockIdx.x * 64;
    #pragma unroll
    for (int q = 0; q < 8; ++q) {
        int g = t + q * 256;           // 0..2047
        int m = g >> 5, k4 = g & 31;
        float4 v = make_float4(0.f, 0.f, 0.f, 0.f);
        int grow = row0 + m;
        if (grow < N_NODES) v = *(const float4*)(H + (size_t)grow * 128 + k4 * 4);
        *(float4*)(&sA[m][k4 * 4]) = v;
    }
    for (int g = t; g < 1280; g += 256) {  // W2: 128x40 = 1280 float4
        int k = g / 10, c4 = g % 10;
        float4 v = *(const float4*)(W2 + k * 40 + c4 * 4);
        sB[c4 * 4 + 0][k] = v.x;
        sB[c4 * 4 + 1][k] = v.y;
        sB[c4 * 4 + 2][k] = v.z;
        sB[c4 * 4 + 3][k] = v.w;
    }
    __syncthreads();
    int tc = t & 3, tr = t >> 2;     // tr 0..63
    int c0 = tc * 10;
    float acc[10] = {};
    for (int k = 0; k < 128; k += 4) {
        float4 a = *(const float4*)(&sA[tr][k]);
        #pragma unroll
        for (int i = 0; i < 10; ++i) {
            float4 b = *(const float4*)(&sB[c0 + i][k]);
            acc[i] += a.x * b.x;
            acc[i] += a.y * b.y;
            acc[i] += a.z * b.z;
            acc[i] += a.w * b.w;
        }
    }
    int grow = row0 + tr;
    if (grow < N_NODES) {
        #pragma unroll
        for (int i = 0; i < 10; ++i) HW[(size_t)grow * 40 + c0 + i] = acc[i];
    }
}

// ---------------- Aggregation layer 2 + b2 + softmax ----------------

__global__ __launch_bounds__(256) void agg2_kernel(const float* __restrict__ HW,
                                                   const int* __restrict__ off,
                                                   const int* __restrict__ esrc,
                                                   const float* __restrict__ enrm,
                                                   const float* __restrict__ dinv,
                                                   const float* __restrict__ b2,
                                                   float* __restrict__ out) {
    int n = blockIdx.x * 4 + (threadIdx.x >> 6);
    int l = threadIdx.x & 63;
    if (n >= N_NODES) return;
    bool act = (l < 40);
    float di = dinv[n];
    float acc = act ? di * di * HW[(size_t)n * 40 + l] : 0.f;
    int e0 = off[n], e1 = off[n + 1];
    for (int e = e0; e < e1; ++e) {
        int s = esrc[e];
        float w = enrm[e];
        if (act) acc += w * HW[(size_t)s * 40 + l];
    }
    if (act) acc += b2[l];
    float m = act ? acc : -1e30f;
    #pragma unroll
    for (int d = 32; d; d >>= 1) m = fmaxf(m, __shfl_xor(m, d, 64));
    float p = act ? expf(acc - m) : 0.f;
    float s = p;
    #pragma unroll
    for (int d = 32; d; d >>= 1) s += __shfl_xor(s, d, 64);
    if (act) out[(size_t)n * 40 + l] = p / s;
}

// ---------------- launch ----------------

extern "C" void kernel_launch(void* const* d_in, const int* in_sizes, int n_in,
                              void* d_out, int out_size, void* d_ws, size_t ws_size,
                              hipStream_t stream) {
    const float* x  = (const float*)d_in[0];
    const int*   ei = (const int*)d_in[1];
    const float* ew = (const float*)d_in[2];
    // d_in[3] = attention (PERIODS=1 -> softmax = 1.0, unused)
    const float* W1 = (const float*)d_in[4];
    const float* b1 = (const float*)d_in[5];
    const float* W2 = (const float*)d_in[6];
    const float* b2 = (const float*)d_in[7];
    float* out = (float*)d_out;

    char* p = (char*)d_ws;
    auto alloc = [&](size_t bytes) -> void* {
        void* r = (void*)p;
        p += (bytes + 511) & ~(size_t)511;
        return r;
    };
    float* deg    = (float*)alloc((size_t)N_NODES * 4);       // becomes dinv
    int*   cursor = (int*)alloc((size_t)N_NODES * 4);
    int*   off    = (int*)alloc((size_t)(N_NODES + 1) * 4);
    int*   bsum   = (int*)alloc(1024 * 4);
    int*   esrc   = (int*)alloc((size_t)N_EDGES * 4);
    float* enrm   = (float*)alloc((size_t)N_EDGES * 4);
    float* XW     = (float*)alloc((size_t)N_NODES * 128 * 4); // reused as HW
    float* H      = (float*)alloc((size_t)N_NODES * 128 * 4);
    float* HW     = XW;

    int nblk_n = (N_NODES + 255) / 256;
    int nblk_e = (N_EDGES + 255) / 256;
    int nblk_s = (N_NODES + 1023) / 1024;   // 98

    hipLaunchKernelGGL(init_kernel,  dim3(nblk_n), dim3(256), 0, stream, deg, cursor);
    hipLaunchKernelGGL(count_kernel, dim3(nblk_e), dim3(256), 0, stream, ei, ew, deg, cursor);
    hipLaunchKernelGGL(dinv_kernel,  dim3(nblk_n), dim3(256), 0, stream, deg);
    hipLaunchKernelGGL(scanA_kernel, dim3(nblk_s), dim3(1024), 0, stream, cursor, off, bsum);
    hipLaunchKernelGGL(scanB_kernel, dim3(1), dim3(1024), 0, stream, bsum, nblk_s);
    hipLaunchKernelGGL(scanC_kernel, dim3(nblk_s), dim3(1024), 0, stream, off, bsum, cursor);
    hipLaunchKernelGGL(fill_kernel,  dim3(nblk_e), dim3(256), 0, stream, ei, ew, deg, cursor, esrc, enrm);

    hipLaunchKernelGGL(gemm1_kernel, dim3((N_NODES + 127) / 128), dim3(256), 0, stream, x, W1, XW);
    hipLaunchKernelGGL(agg1_kernel,  dim3((N_NODES + 3) / 4), dim3(256), 0, stream,
                       XW, off, esrc, enrm, deg, b1, H);
    hipLaunchKernelGGL(gemm2_kernel, dim3((N_NODES + 63) / 64), dim3(256), 0, stream, H, W2, HW);
    hipLaunchKernelGGL(agg2_kernel,  dim3((N_NODES + 3) / 4), dim3(256), 0, stream,
                       HW, off, esrc, enrm, deg, b2, out);
}

// Round 4
// 543.709 us; speedup vs baseline: 1.2707x; 1.2707x over previous
//
#include <hip/hip_runtime.h>
#include <hip/hip_bf16.h>

#define N_NODES 100000
#define N_EDGES 1600000

// ---------------- CSR build ----------------

__global__ void init_kernel(float* deg, int* cursor) {
    int i = blockIdx.x * 256 + threadIdx.x;
    if (i < N_NODES) { deg[i] = 1.0f; cursor[i] = 0; }
}

__global__ void count_kernel(const int* __restrict__ ei, const float* __restrict__ w,
                             float* deg, int* cursor) {
    int e = blockIdx.x * 256 + threadIdx.x;
    if (e < N_EDGES) {
        int c = ei[N_EDGES + e];
        atomicAdd(&deg[c], w[e]);
        atomicAdd(&cursor[c], 1);
    }
}

__global__ void dinv_kernel(float* deg) {
    int i = blockIdx.x * 256 + threadIdx.x;
    if (i < N_NODES) deg[i] = rsqrtf(deg[i]);
}

// per-block exclusive scan; off[i] = block-local exclusive, bsum[b] = block total
__global__ void scanA_kernel(const int* __restrict__ cnt, int* __restrict__ off, int* __restrict__ bsum) {
    __shared__ int s[1024];
    int t = threadIdx.x;
    int i = blockIdx.x * 1024 + t;
    int v = (i < N_NODES) ? cnt[i] : 0;
    s[t] = v; __syncthreads();
    #pragma unroll
    for (int d = 1; d < 1024; d <<= 1) {
        int x = (t >= d) ? s[t - d] : 0;
        __syncthreads();
        s[t] += x;
        __syncthreads();
    }
    if (i < N_NODES) off[i] = s[t] - v;
    if (t == 1023) bsum[blockIdx.x] = s[1023];
}

__global__ void scanB_kernel(int* bsum, int nb) {
    __shared__ int s[1024];
    int t = threadIdx.x;
    int v = (t < nb) ? bsum[t] : 0;
    s[t] = v; __syncthreads();
    #pragma unroll
    for (int d = 1; d < 1024; d <<= 1) {
        int x = (t >= d) ? s[t - d] : 0;
        __syncthreads();
        s[t] += x;
        __syncthreads();
    }
    if (t < nb) bsum[t] = s[t] - v;
}

__global__ void scanC_kernel(int* __restrict__ off, const int* __restrict__ bsum, int* __restrict__ cursor) {
    int i = blockIdx.x * 1024 + threadIdx.x;
    if (i < N_NODES) {
        int o = off[i] + bsum[blockIdx.x];
        off[i] = o;
        cursor[i] = o;
    }
    if (i == 0) off[N_NODES] = N_EDGES;
}

__global__ void fill_kernel(const int* __restrict__ ei, const float* __restrict__ w,
                            const float* __restrict__ dinv, int* cursor,
                            int2* __restrict__ epack) {
    int e = blockIdx.x * 256 + threadIdx.x;
    if (e < N_EDGES) {
        int r = ei[e];
        int c = ei[N_EDGES + e];
        int p = atomicAdd(&cursor[c], 1);
        float nrm = dinv[r] * w[e] * dinv[c];
        epack[p] = make_int2(r, __float_as_int(nrm));
    }
}

// ---------------- GEMM1: XW = X @ W1   (100000x128 @ 128x128) ----------------

__global__ __launch_bounds__(256) void gemm1_kernel(const float* __restrict__ X,
                                                    const float* __restrict__ W,
                                                    float* __restrict__ XW) {
    __shared__ float sA[32][132];   // [k][m]
    __shared__ float sB[32][132];   // [k][n] (128 used)
    int t = threadIdx.x;
    int row0 = blockIdx.x * 128;
    int tc = t & 15, tr = t >> 4;
    int m0 = tr * 8, n0 = tc * 8;
    float acc[8][8] = {};
    for (int kt = 0; kt < 128; kt += 32) {
        #pragma unroll
        for (int q = 0; q < 4; ++q) {
            int g = t + q * 256;          // 0..1023
            int row = g >> 3;
            int c4 = g & 7;
            float4 v = make_float4(0.f, 0.f, 0.f, 0.f);
            int grow = row0 + row;
            if (grow < N_NODES) v = *(const float4*)(X + (size_t)grow * 128 + kt + c4 * 4);
            sA[c4 * 4 + 0][row] = v.x;
            sA[c4 * 4 + 1][row] = v.y;
            sA[c4 * 4 + 2][row] = v.z;
            sA[c4 * 4 + 3][row] = v.w;
        }
        #pragma unroll
        for (int q = 0; q < 4; ++q) {
            int g = t + q * 256;
            int k = g >> 5, n4 = g & 31;
            *(float4*)(&sB[k][n4 * 4]) = *(const float4*)(W + (kt + k) * 128 + n4 * 4);
        }
        __syncthreads();
        #pragma unroll
        for (int k = 0; k < 32; ++k) {
            float4 a0 = *(const float4*)(&sA[k][m0]);
            float4 a1 = *(const float4*)(&sA[k][m0 + 4]);
            float4 b0 = *(const float4*)(&sB[k][n0]);
            float4 b1v = *(const float4*)(&sB[k][n0 + 4]);
            float a[8] = {a0.x, a0.y, a0.z, a0.w, a1.x, a1.y, a1.z, a1.w};
            float b[8] = {b0.x, b0.y, b0.z, b0.w, b1v.x, b1v.y, b1v.z, b1v.w};
            #pragma unroll
            for (int j = 0; j < 8; ++j)
                #pragma unroll
                for (int i = 0; i < 8; ++i) acc[j][i] += a[j] * b[i];
        }
        __syncthreads();
    }
    #pragma unroll
    for (int j = 0; j < 8; ++j) {
        int grow = row0 + m0 + j;
        if (grow < N_NODES) {
            float4 v0 = {acc[j][0], acc[j][1], acc[j][2], acc[j][3]};
            float4 v1 = {acc[j][4], acc[j][5], acc[j][6], acc[j][7]};
            *(float4*)(XW + (size_t)grow * 128 + n0) = v0;
            *(float4*)(XW + (size_t)grow * 128 + n0 + 4) = v1;
        }
    }
}

// ---------------- Aggregation layer 1 (wave per node, float2 lanes, 4-edge ILP) ----------------

__global__ __launch_bounds__(256) void agg1_kernel(const float* __restrict__ XW,
                                                   const int* __restrict__ off,
                                                   const int2* __restrict__ epack,
                                                   const float* __restrict__ dinv,
                                                   const float* __restrict__ b1,
                                                   float* __restrict__ H) {
    int n = blockIdx.x * 4 + (threadIdx.x >> 6);
    int l = threadIdx.x & 63;
    if (n >= N_NODES) return;
    const float2* XW2 = (const float2*)XW;
    float di = dinv[n];
    float self = di * di;
    float2 v = XW2[(size_t)n * 64 + l];
    float a0x = self * v.x, a0y = self * v.y;
    float a1x = 0.f, a1y = 0.f, a2x = 0.f, a2y = 0.f, a3x = 0.f, a3y = 0.f;
    int e0 = off[n], e1 = off[n + 1];
    for (int base = e0; base < e1; base += 4) {
        int last = e1 - 1;
        int i1 = min(base + 1, last), i2 = min(base + 2, last), i3 = min(base + 3, last);
        int2 p0 = epack[base], p1 = epack[i1], p2 = epack[i2], p3 = epack[i3];
        float w0 = __int_as_float(p0.y);
        float w1 = (base + 1 < e1) ? __int_as_float(p1.y) : 0.f;
        float w2 = (base + 2 < e1) ? __int_as_float(p2.y) : 0.f;
        float w3 = (base + 3 < e1) ? __int_as_float(p3.y) : 0.f;
        float2 g0 = XW2[(size_t)p0.x * 64 + l];
        float2 g1 = XW2[(size_t)p1.x * 64 + l];
        float2 g2 = XW2[(size_t)p2.x * 64 + l];
        float2 g3 = XW2[(size_t)p3.x * 64 + l];
        a0x += w0 * g0.x; a0y += w0 * g0.y;
        a1x += w1 * g1.x; a1y += w1 * g1.y;
        a2x += w2 * g2.x; a2y += w2 * g2.y;
        a3x += w3 * g3.x; a3y += w3 * g3.y;
    }
    float ax = (a0x + a1x) + (a2x + a3x);
    float ay = (a0y + a1y) + (a2y + a3y);
    float2 bb = ((const float2*)b1)[l];
    float2 outv;
    outv.x = fmaxf(ax + bb.x, 0.f);
    outv.y = fmaxf(ay + bb.y, 0.f);
    ((float2*)H)[(size_t)n * 64 + l] = outv;
}

// ---------------- GEMM2: HW = H @ W2   (100000x128 @ 128x40) ----------------

__global__ __launch_bounds__(256) void gemm2_kernel(const float* __restrict__ H,
                                                    const float* __restrict__ W2,
                                                    float* __restrict__ HW) {
    __shared__ float sA[64][132];  // [m][k]
    __shared__ float sB[40][132];  // [c][k]
    int t = threadIdx.x;
    int row0 = blockIdx.x * 64;
    #pragma unroll
    for (int q = 0; q < 8; ++q) {
        int g = t + q * 256;           // 0..2047
        int m = g >> 5, k4 = g & 31;
        float4 v = make_float4(0.f, 0.f, 0.f, 0.f);
        int grow = row0 + m;
        if (grow < N_NODES) v = *(const float4*)(H + (size_t)grow * 128 + k4 * 4);
        *(float4*)(&sA[m][k4 * 4]) = v;
    }
    for (int g = t; g < 1280; g += 256) {  // W2: 128x40 = 1280 float4
        int k = g / 10, c4 = g % 10;
        float4 v = *(const float4*)(W2 + k * 40 + c4 * 4);
        sB[c4 * 4 + 0][k] = v.x;
        sB[c4 * 4 + 1][k] = v.y;
        sB[c4 * 4 + 2][k] = v.z;
        sB[c4 * 4 + 3][k] = v.w;
    }
    __syncthreads();
    int tc = t & 3, tr = t >> 2;     // tr 0..63
    int c0 = tc * 10;
    float acc[10] = {};
    for (int k = 0; k < 128; k += 4) {
        float4 a = *(const float4*)(&sA[tr][k]);
        #pragma unroll
        for (int i = 0; i < 10; ++i) {
            float4 b = *(const float4*)(&sB[c0 + i][k]);
            acc[i] += a.x * b.x;
            acc[i] += a.y * b.y;
            acc[i] += a.z * b.z;
            acc[i] += a.w * b.w;
        }
    }
    int grow = row0 + tr;
    if (grow < N_NODES) {
        #pragma unroll
        for (int i = 0; i < 10; ++i) HW[(size_t)grow * 40 + c0 + i] = acc[i];
    }
}

// ---------------- Aggregation layer 2 (8-edge ILP) + b2 + softmax ----------------

__global__ __launch_bounds__(256) void agg2_kernel(const float* __restrict__ HW,
                                                   const int* __restrict__ off,
                                                   const int2* __restrict__ epack,
                                                   const float* __restrict__ dinv,
                                                   const float* __restrict__ b2,
                                                   float* __restrict__ out) {
    int n = blockIdx.x * 4 + (threadIdx.x >> 6);
    int l = threadIdx.x & 63;
    if (n >= N_NODES) return;
    bool act = (l < 40);
    int ll = act ? l : l - 40;   // idle lanes mirror low features: loads stay in-row
    float di = dinv[n];
    float acc[8];
    acc[0] = di * di * HW[(size_t)n * 40 + ll];
    #pragma unroll
    for (int k = 1; k < 8; ++k) acc[k] = 0.f;
    int e0 = off[n], e1 = off[n + 1];
    for (int base = e0; base < e1; base += 8) {
        int last = e1 - 1;
        int2 p[8];
        float w[8];
        #pragma unroll
        for (int k = 0; k < 8; ++k) {
            int e = base + k;
            int idx = min(e, last);
            p[k] = epack[idx];
            w[k] = (e < e1) ? __int_as_float(p[k].y) : 0.f;
        }
        #pragma unroll
        for (int k = 0; k < 8; ++k) {
            float g = HW[(size_t)p[k].x * 40 + ll];
            acc[k] += w[k] * g;
        }
    }
    float a = ((acc[0] + acc[1]) + (acc[2] + acc[3])) + ((acc[4] + acc[5]) + (acc[6] + acc[7]));
    a += b2[ll];
    float m = act ? a : -1e30f;
    #pragma unroll
    for (int d = 32; d; d >>= 1) m = fmaxf(m, __shfl_xor(m, d, 64));
    float pexp = act ? expf(a - m) : 0.f;
    float s = pexp;
    #pragma unroll
    for (int d = 32; d; d >>= 1) s += __shfl_xor(s, d, 64);
    if (act) out[(size_t)n * 40 + l] = pexp / s;
}

// ---------------- launch ----------------

extern "C" void kernel_launch(void* const* d_in, const int* in_sizes, int n_in,
                              void* d_out, int out_size, void* d_ws, size_t ws_size,
                              hipStream_t stream) {
    const float* x  = (const float*)d_in[0];
    const int*   ei = (const int*)d_in[1];
    const float* ew = (const float*)d_in[2];
    // d_in[3] = attention (PERIODS=1 -> softmax = 1.0, unused)
    const float* W1 = (const float*)d_in[4];
    const float* b1 = (const float*)d_in[5];
    const float* W2 = (const float*)d_in[6];
    const float* b2 = (const float*)d_in[7];
    float* out = (float*)d_out;

    char* p = (char*)d_ws;
    auto alloc = [&](size_t bytes) -> void* {
        void* r = (void*)p;
        p += (bytes + 511) & ~(size_t)511;
        return r;
    };
    float* deg    = (float*)alloc((size_t)N_NODES * 4);       // becomes dinv
    int*   cursor = (int*)alloc((size_t)N_NODES * 4);
    int*   off    = (int*)alloc((size_t)(N_NODES + 1) * 4);
    int*   bsum   = (int*)alloc(1024 * 4);
    int2*  epack  = (int2*)alloc((size_t)N_EDGES * 8);
    float* XW     = (float*)alloc((size_t)N_NODES * 128 * 4); // reused as HW
    float* H      = (float*)alloc((size_t)N_NODES * 128 * 4);
    float* HW     = XW;

    int nblk_n = (N_NODES + 255) / 256;
    int nblk_e = (N_EDGES + 255) / 256;
    int nblk_s = (N_NODES + 1023) / 1024;   // 98

    hipLaunchKernelGGL(init_kernel,  dim3(nblk_n), dim3(256), 0, stream, deg, cursor);
    hipLaunchKernelGGL(count_kernel, dim3(nblk_e), dim3(256), 0, stream, ei, ew, deg, cursor);
    hipLaunchKernelGGL(dinv_kernel,  dim3(nblk_n), dim3(256), 0, stream, deg);
    hipLaunchKernelGGL(scanA_kernel, dim3(nblk_s), dim3(1024), 0, stream, cursor, off, bsum);
    hipLaunchKernelGGL(scanB_kernel, dim3(1), dim3(1024), 0, stream, bsum, nblk_s);
    hipLaunchKernelGGL(scanC_kernel, dim3(nblk_s), dim3(1024), 0, stream, off, bsum, cursor);
    hipLaunchKernelGGL(fill_kernel,  dim3(nblk_e), dim3(256), 0, stream, ei, ew, deg, cursor, epack);

    hipLaunchKernelGGL(gemm1_kernel, dim3((N_NODES + 127) / 128), dim3(256), 0, stream, x, W1, XW);
    hipLaunchKernelGGL(agg1_kernel,  dim3((N_NODES + 3) / 4), dim3(256), 0, stream,
                       XW, off, epack, deg, b1, H);
    hipLaunchKernelGGL(gemm2_kernel, dim3((N_NODES + 63) / 64), dim3(256), 0, stream, H, W2, HW);
    hipLaunchKernelGGL(agg2_kernel,  dim3((N_NODES + 3) / 4), dim3(256), 0, stream,
                       HW, off, epack, deg, b2, out);
}

// Round 8
// 429.290 us; speedup vs baseline: 1.6093x; 1.2665x over previous
//
#include <hip/hip_runtime.h>
#include <hip/hip_bf16.h>

#define N_NODES 100000
#define N_EDGES 1600000

// ---------------- CSR build (1 atomic per edge, packed 64-bit) ----------------

__global__ void init_kernel(unsigned long long* packed) {
    int i = blockIdx.x * 256 + threadIdx.x;
    if (i < N_NODES) packed[i] = 0ULL;
}

// one 64-bit atomic per edge: high 32 = count, low 32 = sum(w * 2^20)
__global__ void count_kernel(const int* __restrict__ ei, const float* __restrict__ w,
                             unsigned long long* packed, int* __restrict__ seq) {
    int e = blockIdx.x * 256 + threadIdx.x;
    if (e < N_EDGES) {
        int c = ei[N_EDGES + e];
        unsigned int fw = (unsigned int)rintf(w[e] * 1048576.0f);
        unsigned long long old = atomicAdd(&packed[c], (1ULL << 32) | (unsigned long long)fw);
        seq[e] = (int)(old >> 32);
    }
}

__global__ void dinv_kernel(const unsigned long long* __restrict__ packed, float* __restrict__ dinv) {
    int i = blockIdx.x * 256 + threadIdx.x;
    if (i < N_NODES) {
        float deg = 1.0f + (float)(unsigned int)(packed[i] & 0xffffffffULL) * (1.0f / 1048576.0f);
        dinv[i] = rsqrtf(deg);
    }
}

// per-block exclusive scan over counts (packed>>32)
__global__ void scanA_kernel(const unsigned long long* __restrict__ packed,
                             int* __restrict__ off, int* __restrict__ bsum) {
    __shared__ int s[1024];
    int t = threadIdx.x;
    int i = blockIdx.x * 1024 + t;
    int v = (i < N_NODES) ? (int)(packed[i] >> 32) : 0;
    s[t] = v; __syncthreads();
    #pragma unroll
    for (int d = 1; d < 1024; d <<= 1) {
        int x = (t >= d) ? s[t - d] : 0;
        __syncthreads();
        s[t] += x;
        __syncthreads();
    }
    if (i < N_NODES) off[i] = s[t] - v;
    if (t == 1023) bsum[blockIdx.x] = s[1023];
}

__global__ void scanB_kernel(int* bsum, int nb) {
    __shared__ int s[1024];
    int t = threadIdx.x;
    int v = (t < nb) ? bsum[t] : 0;
    s[t] = v; __syncthreads();
    #pragma unroll
    for (int d = 1; d < 1024; d <<= 1) {
        int x = (t >= d) ? s[t - d] : 0;
        __syncthreads();
        s[t] += x;
        __syncthreads();
    }
    if (t < nb) bsum[t] = s[t] - v;
}

__global__ void scanC_kernel(int* __restrict__ off, const int* __restrict__ bsum) {
    int i = blockIdx.x * 1024 + threadIdx.x;
    if (i < N_NODES) off[i] += bsum[blockIdx.x];
    if (i == 0) off[N_NODES] = N_EDGES;
}

// atomic-free fill: slot = off[dst] + seq[e]
__global__ void fill_kernel(const int* __restrict__ ei, const float* __restrict__ w,
                            const float* __restrict__ dinv, const int* __restrict__ off,
                            const int* __restrict__ seq, int2* __restrict__ epack) {
    int e = blockIdx.x * 256 + threadIdx.x;
    if (e < N_EDGES) {
        int r = ei[e];
        int c = ei[N_EDGES + e];
        int p = off[c] + seq[e];
        float nrm = dinv[r] * w[e] * dinv[c];
        epack[p] = make_int2(r, __float_as_int(nrm));
    }
}

// ---------------- GEMM1: XW = X @ W1   (100000x128 @ 128x128) ----------------

__global__ __launch_bounds__(256) void gemm1_kernel(const float* __restrict__ X,
                                                    const float* __restrict__ W,
                                                    float* __restrict__ XW) {
    __shared__ float sA[32][132];   // [k][m]
    __shared__ float sB[32][132];   // [k][n] (128 used)
    int t = threadIdx.x;
    int row0 = blockIdx.x * 128;
    int tc = t & 15, tr = t >> 4;
    int m0 = tr * 8, n0 = tc * 8;
    float acc[8][8] = {};
    for (int kt = 0; kt < 128; kt += 32) {
        #pragma unroll
        for (int q = 0; q < 4; ++q) {
            int g = t + q * 256;          // 0..1023
            int row = g >> 3;
            int c4 = g & 7;
            float4 v = make_float4(0.f, 0.f, 0.f, 0.f);
            int grow = row0 + row;
            if (grow < N_NODES) v = *(const float4*)(X + (size_t)grow * 128 + kt + c4 * 4);
            sA[c4 * 4 + 0][row] = v.x;
            sA[c4 * 4 + 1][row] = v.y;
            sA[c4 * 4 + 2][row] = v.z;
            sA[c4 * 4 + 3][row] = v.w;
        }
        #pragma unroll
        for (int q = 0; q < 4; ++q) {
            int g = t + q * 256;
            int k = g >> 5, n4 = g & 31;
            *(float4*)(&sB[k][n4 * 4]) = *(const float4*)(W + (kt + k) * 128 + n4 * 4);
        }
        __syncthreads();
        #pragma unroll
        for (int k = 0; k < 32; ++k) {
            float4 a0 = *(const float4*)(&sA[k][m0]);
            float4 a1 = *(const float4*)(&sA[k][m0 + 4]);
            float4 b0 = *(const float4*)(&sB[k][n0]);
            float4 b1v = *(const float4*)(&sB[k][n0 + 4]);
            float a[8] = {a0.x, a0.y, a0.z, a0.w, a1.x, a1.y, a1.z, a1.w};
            float b[8] = {b0.x, b0.y, b0.z, b0.w, b1v.x, b1v.y, b1v.z, b1v.w};
            #pragma unroll
            for (int j = 0; j < 8; ++j)
                #pragma unroll
                for (int i = 0; i < 8; ++i) acc[j][i] += a[j] * b[i];
        }
        __syncthreads();
    }
    #pragma unroll
    for (int j = 0; j < 8; ++j) {
        int grow = row0 + m0 + j;
        if (grow < N_NODES) {
            float4 v0 = {acc[j][0], acc[j][1], acc[j][2], acc[j][3]};
            float4 v1 = {acc[j][4], acc[j][5], acc[j][6], acc[j][7]};
            *(float4*)(XW + (size_t)grow * 128 + n0) = v0;
            *(float4*)(XW + (size_t)grow * 128 + n0 + 4) = v1;
        }
    }
}

// ---------------- Aggregation layer 1 (wave per node, float2 lanes, 8-edge ILP) ----------------

__global__ __launch_bounds__(256) void agg1_kernel(const float* __restrict__ XW,
                                                   const int* __restrict__ off,
                                                   const int2* __restrict__ epack,
                                                   const float* __restrict__ dinv,
                                                   const float* __restrict__ b1,
                                                   float* __restrict__ H) {
    int n = blockIdx.x * 4 + (threadIdx.x >> 6);
    int l = threadIdx.x & 63;
    if (n >= N_NODES) return;
    const float2* XW2 = (const float2*)XW;
    float di = dinv[n];
    float self = di * di;
    float2 v = XW2[(size_t)n * 64 + l];
    float accx[8], accy[8];
    accx[0] = self * v.x; accy[0] = self * v.y;
    #pragma unroll
    for (int k = 1; k < 8; ++k) { accx[k] = 0.f; accy[k] = 0.f; }
    int e0 = off[n], e1 = off[n + 1];
    for (int base = e0; base < e1; base += 8) {
        int last = e1 - 1;
        int2 p[8];
        float w[8];
        #pragma unroll
        for (int k = 0; k < 8; ++k) {
            int e = base + k;
            int idx = min(e, last);
            p[k] = epack[idx];
            w[k] = (e < e1) ? __int_as_float(p[k].y) : 0.f;
        }
        #pragma unroll
        for (int k = 0; k < 8; ++k) {
            float2 g = XW2[(size_t)p[k].x * 64 + l];
            accx[k] += w[k] * g.x;
            accy[k] += w[k] * g.y;
        }
    }
    float ax = ((accx[0] + accx[1]) + (accx[2] + accx[3])) + ((accx[4] + accx[5]) + (accx[6] + accx[7]));
    float ay = ((accy[0] + accy[1]) + (accy[2] + accy[3])) + ((accy[4] + accy[5]) + (accy[6] + accy[7]));
    float2 bb = ((const float2*)b1)[l];
    float2 outv;
    outv.x = fmaxf(ax + bb.x, 0.f);
    outv.y = fmaxf(ay + bb.y, 0.f);
    ((float2*)H)[(size_t)n * 64 + l] = outv;
}

// ---------------- GEMM2: HW = H @ W2   (100000x128 @ 128x40) ----------------

__global__ __launch_bounds__(256) void gemm2_kernel(const float* __restrict__ H,
                                                    const float* __restrict__ W2,
                                                    float* __restrict__ HW) {
    __shared__ float sA[64][132];  // [m][k]
    __shared__ float sB[40][132];  // [c][k]
    int t = threadIdx.x;
    int row0 = blockIdx.x * 64;
    #pragma unroll
    for (int q = 0; q < 8; ++q) {
        int g = t + q * 256;           // 0..2047
        int m = g >> 5, k4 = g & 31;
        float4 v = make_float4(0.f, 0.f, 0.f, 0.f);
        int grow = row0 + m;
        if (grow < N_NODES) v = *(const float4*)(H + (size_t)grow * 128 + k4 * 4);
        *(float4*)(&sA[m][k4 * 4]) = v;
    }
    for (int g = t; g < 1280; g += 256) {  // W2: 128x40 = 1280 float4
        int k = g / 10, c4 = g % 10;
        float4 v = *(const float4*)(W2 + k * 40 + c4 * 4);
        sB[c4 * 4 + 0][k] = v.x;
        sB[c4 * 4 + 1][k] = v.y;
        sB[c4 * 4 + 2][k] = v.z;
        sB[c4 * 4 + 3][k] = v.w;
    }
    __syncthreads();
    int tc = t & 3, tr = t >> 2;     // tr 0..63
    int c0 = tc * 10;
    float acc[10] = {};
    for (int k = 0; k < 128; k += 4) {
        float4 a = *(const float4*)(&sA[tr][k]);
        #pragma unroll
        for (int i = 0; i < 10; ++i) {
            float4 b = *(const float4*)(&sB[c0 + i][k]);
            acc[i] += a.x * b.x;
            acc[i] += a.y * b.y;
            acc[i] += a.z * b.z;
            acc[i] += a.w * b.w;
        }
    }
    int grow = row0 + tr;
    if (grow < N_NODES) {
        #pragma unroll
        for (int i = 0; i < 10; ++i) HW[(size_t)grow * 40 + c0 + i] = acc[i];
    }
}

// ---------------- Aggregation layer 2 (8-edge ILP) + b2 + softmax ----------------

__global__ __launch_bounds__(256) void agg2_kernel(const float* __restrict__ HW,
                                                   const int* __restrict__ off,
                                                   const int2* __restrict__ epack,
                                                   const float* __restrict__ dinv,
                                                   const float* __restrict__ b2,
                                                   float* __restrict__ out) {
    int n = blockIdx.x * 4 + (threadIdx.x >> 6);
    int l = threadIdx.x & 63;
    if (n >= N_NODES) return;
    bool act = (l < 40);
    int ll = act ? l : l - 40;   // idle lanes mirror low features: loads stay in-row
    float di = dinv[n];
    float acc[8];
    acc[0] = di * di * HW[(size_t)n * 40 + ll];
    #pragma unroll
    for (int k = 1; k < 8; ++k) acc[k] = 0.f;
    int e0 = off[n], e1 = off[n + 1];
    for (int base = e0; base < e1; base += 8) {
        int last = e1 - 1;
        int2 p[8];
        float w[8];
        #pragma unroll
        for (int k = 0; k < 8; ++k) {
            int e = base + k;
            int idx = min(e, last);
            p[k] = epack[idx];
            w[k] = (e < e1) ? __int_as_float(p[k].y) : 0.f;
        }
        #pragma unroll
        for (int k = 0; k < 8; ++k) {
            float g = HW[(size_t)p[k].x * 40 + ll];
            acc[k] += w[k] * g;
        }
    }
    float a = ((acc[0] + acc[1]) + (acc[2] + acc[3])) + ((acc[4] + acc[5]) + (acc[6] + acc[7]));
    a += b2[ll];
    float m = act ? a : -1e30f;
    #pragma unroll
    for (int d = 32; d; d >>= 1) m = fmaxf(m, __shfl_xor(m, d, 64));
    float pexp = act ? expf(a - m) : 0.f;
    float s = pexp;
    #pragma unroll
    for (int d = 32; d; d >>= 1) s += __shfl_xor(s, d, 64);
    if (act) out[(size_t)n * 40 + l] = pexp / s;
}

// ---------------- launch ----------------

extern "C" void kernel_launch(void* const* d_in, const int* in_sizes, int n_in,
                              void* d_out, int out_size, void* d_ws, size_t ws_size,
                              hipStream_t stream) {
    const float* x  = (const float*)d_in[0];
    const int*   ei = (const int*)d_in[1];
    const float* ew = (const float*)d_in[2];
    // d_in[3] = attention (PERIODS=1 -> softmax = 1.0, unused)
    const float* W1 = (const float*)d_in[4];
    const float* b1 = (const float*)d_in[5];
    const float* W2 = (const float*)d_in[6];
    const float* b2 = (const float*)d_in[7];
    float* out = (float*)d_out;

    char* p = (char*)d_ws;
    auto alloc = [&](size_t bytes) -> void* {
        void* r = (void*)p;
        p += (bytes + 511) & ~(size_t)511;
        return r;
    };
    unsigned long long* packed = (unsigned long long*)alloc((size_t)N_NODES * 8);
    float* dinv   = (float*)alloc((size_t)N_NODES * 4);
    int*   off    = (int*)alloc((size_t)(N_NODES + 1) * 4);
    int*   bsum   = (int*)alloc(1024 * 4);
    int*   seq    = (int*)alloc((size_t)N_EDGES * 4);
    int2*  epack  = (int2*)alloc((size_t)N_EDGES * 8);
    float* XW     = (float*)alloc((size_t)N_NODES * 128 * 4); // reused as HW
    float* H      = (float*)alloc((size_t)N_NODES * 128 * 4);
    float* HW     = XW;

    int nblk_n = (N_NODES + 255) / 256;
    int nblk_e = (N_EDGES + 255) / 256;
    int nblk_s = (N_NODES + 1023) / 1024;   // 98

    hipLaunchKernelGGL(init_kernel,  dim3(nblk_n), dim3(256), 0, stream, packed);
    hipLaunchKernelGGL(count_kernel, dim3(nblk_e), dim3(256), 0, stream, ei, ew, packed, seq);
    hipLaunchKernelGGL(dinv_kernel,  dim3(nblk_n), dim3(256), 0, stream, packed, dinv);
    hipLaunchKernelGGL(scanA_kernel, dim3(nblk_s), dim3(1024), 0, stream, packed, off, bsum);
    hipLaunchKernelGGL(scanB_kernel, dim3(1), dim3(1024), 0, stream, bsum, nblk_s);
    hipLaunchKernelGGL(scanC_kernel, dim3(nblk_s), dim3(1024), 0, stream, off, bsum);
    hipLaunchKernelGGL(fill_kernel,  dim3(nblk_e), dim3(256), 0, stream, ei, ew, dinv, off, seq, epack);

    hipLaunchKernelGGL(gemm1_kernel, dim3((N_NODES + 127) / 128), dim3(256), 0, stream, x, W1, XW);
    hipLaunchKernelGGL(agg1_kernel,  dim3((N_NODES + 3) / 4), dim3(256), 0, stream,
                       XW, off, epack, dinv, b1, H);
    hipLaunchKernelGGL(gemm2_kernel, dim3((N_NODES + 63) / 64), dim3(256), 0, stream, H, W2, HW);
    hipLaunchKernelGGL(agg2_kernel,  dim3((N_NODES + 3) / 4), dim3(256), 0, stream,
                       HW, off, epack, dinv, b2, out);
}

// Round 10
// 391.286 us; speedup vs baseline: 1.7656x; 1.0971x over previous
//
#include <hip/hip_runtime.h>
#include <hip/hip_bf16.h>

#define N_NODES 100000
#define N_EDGES 1600000

// ---------------- CSR build (1 atomic per edge, packed 64-bit) ----------------

__global__ void init_kernel(unsigned long long* packed) {
    int i = blockIdx.x * 256 + threadIdx.x;
    if (i < N_NODES) packed[i] = 0ULL;
}

// one 64-bit atomic per edge: high 32 = count, low 32 = sum(w * 2^20)
__global__ void count_kernel(const int* __restrict__ ei, const float* __restrict__ w,
                             unsigned long long* packed, int* __restrict__ seq) {
    int e = blockIdx.x * 256 + threadIdx.x;
    if (e < N_EDGES) {
        int c = ei[N_EDGES + e];
        unsigned int fw = (unsigned int)rintf(w[e] * 1048576.0f);
        unsigned long long old = atomicAdd(&packed[c], (1ULL << 32) | (unsigned long long)fw);
        seq[e] = (int)(old >> 32);
    }
}

// per-block exclusive scan over counts (packed>>32); also computes dinv (fused)
__global__ void scanA_kernel(const unsigned long long* __restrict__ packed,
                             int* __restrict__ off, int* __restrict__ bsum,
                             float* __restrict__ dinv) {
    __shared__ int s[1024];
    int t = threadIdx.x;
    int i = blockIdx.x * 1024 + t;
    unsigned long long pk = (i < N_NODES) ? packed[i] : 0ULL;
    int v = (int)(pk >> 32);
    if (i < N_NODES) {
        float deg = 1.0f + (float)(unsigned int)(pk & 0xffffffffULL) * (1.0f / 1048576.0f);
        dinv[i] = rsqrtf(deg);
    }
    s[t] = v; __syncthreads();
    #pragma unroll
    for (int d = 1; d < 1024; d <<= 1) {
        int x = (t >= d) ? s[t - d] : 0;
        __syncthreads();
        s[t] += x;
        __syncthreads();
    }
    if (i < N_NODES) off[i] = s[t] - v;
    if (t == 1023) bsum[blockIdx.x] = s[1023];
}

__global__ void scanB_kernel(int* bsum, int nb) {
    __shared__ int s[1024];
    int t = threadIdx.x;
    int v = (t < nb) ? bsum[t] : 0;
    s[t] = v; __syncthreads();
    #pragma unroll
    for (int d = 1; d < 1024; d <<= 1) {
        int x = (t >= d) ? s[t - d] : 0;
        __syncthreads();
        s[t] += x;
        __syncthreads();
    }
    if (t < nb) bsum[t] = s[t] - v;
}

__global__ void scanC_kernel(int* __restrict__ off, const int* __restrict__ bsum) {
    int i = blockIdx.x * 1024 + threadIdx.x;
    if (i < N_NODES) off[i] += bsum[blockIdx.x];
    if (i == 0) off[N_NODES] = N_EDGES;
}

// atomic-free fill: slot = off[dst] + seq[e]
__global__ void fill_kernel(const int* __restrict__ ei, const float* __restrict__ w,
                            const float* __restrict__ dinv, const int* __restrict__ off,
                            const int* __restrict__ seq, int2* __restrict__ epack) {
    int e = blockIdx.x * 256 + threadIdx.x;
    if (e < N_EDGES) {
        int r = ei[e];
        int c = ei[N_EDGES + e];
        int p = off[c] + seq[e];
        float nrm = dinv[r] * w[e] * dinv[c];
        epack[p] = make_int2(r, __float_as_int(nrm));
    }
}

// ---------------- GEMM1: XW = X @ W1   (100000x128 @ 128x128) ----------------

__global__ __launch_bounds__(256) void gemm1_kernel(const float* __restrict__ X,
                                                    const float* __restrict__ W,
                                                    float* __restrict__ XW) {
    __shared__ float sA[32][132];   // [k][m]
    __shared__ float sB[32][132];   // [k][n] (128 used)
    int t = threadIdx.x;
    int row0 = blockIdx.x * 128;
    int tc = t & 15, tr = t >> 4;
    int m0 = tr * 8, n0 = tc * 8;
    float acc[8][8] = {};
    for (int kt = 0; kt < 128; kt += 32) {
        #pragma unroll
        for (int q = 0; q < 4; ++q) {
            int g = t + q * 256;          // 0..1023
            int row = g >> 3;
            int c4 = g & 7;
            float4 v = make_float4(0.f, 0.f, 0.f, 0.f);
            int grow = row0 + row;
            if (grow < N_NODES) v = *(const float4*)(X + (size_t)grow * 128 + kt + c4 * 4);
            sA[c4 * 4 + 0][row] = v.x;
            sA[c4 * 4 + 1][row] = v.y;
            sA[c4 * 4 + 2][row] = v.z;
            sA[c4 * 4 + 3][row] = v.w;
        }
        #pragma unroll
        for (int q = 0; q < 4; ++q) {
            int g = t + q * 256;
            int k = g >> 5, n4 = g & 31;
            *(float4*)(&sB[k][n4 * 4]) = *(const float4*)(W + (kt + k) * 128 + n4 * 4);
        }
        __syncthreads();
        #pragma unroll
        for (int k = 0; k < 32; ++k) {
            float4 a0 = *(const float4*)(&sA[k][m0]);
            float4 a1 = *(const float4*)(&sA[k][m0 + 4]);
            float4 b0 = *(const float4*)(&sB[k][n0]);
            float4 b1v = *(const float4*)(&sB[k][n0 + 4]);
            float a[8] = {a0.x, a0.y, a0.z, a0.w, a1.x, a1.y, a1.z, a1.w};
            float b[8] = {b0.x, b0.y, b0.z, b0.w, b1v.x, b1v.y, b1v.z, b1v.w};
            #pragma unroll
            for (int j = 0; j < 8; ++j)
                #pragma unroll
                for (int i = 0; i < 8; ++i) acc[j][i] += a[j] * b[i];
        }
        __syncthreads();
    }
    #pragma unroll
    for (int j = 0; j < 8; ++j) {
        int grow = row0 + m0 + j;
        if (grow < N_NODES) {
            float4 v0 = {acc[j][0], acc[j][1], acc[j][2], acc[j][3]};
            float4 v1 = {acc[j][4], acc[j][5], acc[j][6], acc[j][7]};
            *(float4*)(XW + (size_t)grow * 128 + n0) = v0;
            *(float4*)(XW + (size_t)grow * 128 + n0 + 4) = v1;
        }
    }
}

// ---- Fused aggregation-1 + bias + relu + GEMM2 (HW = relu(Anorm@XW + b1) @ W2) ----
// wave per node; 8-edge ILP gather; per-wave H row staged to LDS; 40 lanes do the
// 128-deep dot with W2 staged in LDS. Grid = exactly N_NODES/4 blocks (100000%4==0).

__global__ __launch_bounds__(256) void agg1f_kernel(const float* __restrict__ XW,
                                                    const int* __restrict__ off,
                                                    const int2* __restrict__ epack,
                                                    const float* __restrict__ dinv,
                                                    const float* __restrict__ b1,
                                                    const float* __restrict__ W2,
                                                    float* __restrict__ HW) {
    __shared__ __align__(16) float sW2[5120];   // [k][c] = k*40+c, 20 KB
    __shared__ __align__(16) float sH[4][128];  // one H row per wave
    int t = threadIdx.x;
    // stage W2 (1280 float4 / 256 threads = 5 each), coalesced copy
    #pragma unroll
    for (int q = 0; q < 5; ++q) {
        int g = t + q * 256;
        ((float4*)sW2)[g] = ((const float4*)W2)[g];
    }
    __syncthreads();

    int wv = t >> 6;
    int n = blockIdx.x * 4 + wv;
    int l = t & 63;
    const float2* XW2 = (const float2*)XW;
    float di = dinv[n];
    float self = di * di;
    float2 v = XW2[(size_t)n * 64 + l];
    float accx[8], accy[8];
    accx[0] = self * v.x; accy[0] = self * v.y;
    #pragma unroll
    for (int k = 1; k < 8; ++k) { accx[k] = 0.f; accy[k] = 0.f; }
    int e0 = off[n], e1 = off[n + 1];
    for (int base = e0; base < e1; base += 8) {
        int last = e1 - 1;
        int2 p[8];
        float w[8];
        #pragma unroll
        for (int k = 0; k < 8; ++k) {
            int e = base + k;
            int idx = min(e, last);
            p[k] = epack[idx];
            w[k] = (e < e1) ? __int_as_float(p[k].y) : 0.f;
        }
        #pragma unroll
        for (int k = 0; k < 8; ++k) {
            float2 g = XW2[(size_t)p[k].x * 64 + l];
            accx[k] += w[k] * g.x;
            accy[k] += w[k] * g.y;
        }
    }
    float ax = ((accx[0] + accx[1]) + (accx[2] + accx[3])) + ((accx[4] + accx[5]) + (accx[6] + accx[7]));
    float ay = ((accy[0] + accy[1]) + (accy[2] + accy[3])) + ((accy[4] + accy[5]) + (accy[6] + accy[7]));
    float2 bb = ((const float2*)b1)[l];
    float hx = fmaxf(ax + bb.x, 0.f);
    float hy = fmaxf(ay + bb.y, 0.f);
    ((float2*)sH[wv])[l] = make_float2(hx, hy);
    __syncthreads();   // uniform: all nodes valid (grid exactly covers N_NODES)

    // per-wave GEMM2 row: lanes 0..39 each compute one output column
    if (l < 40) {
        const float* hrow = sH[wv];
        float dot = 0.f;
        #pragma unroll 4
        for (int k = 0; k < 128; k += 4) {
            float4 h4 = *(const float4*)(hrow + k);
            dot += h4.x * sW2[(k + 0) * 40 + l];
            dot += h4.y * sW2[(k + 1) * 40 + l];
            dot += h4.z * sW2[(k + 2) * 40 + l];
            dot += h4.w * sW2[(k + 3) * 40 + l];
        }
        HW[(size_t)n * 40 + l] = dot;
    }
}

// ---------------- Aggregation layer 2 (8-edge ILP) + b2 + softmax ----------------

__global__ __launch_bounds__(256) void agg2_kernel(const float* __restrict__ HW,
                                                   const int* __restrict__ off,
                                                   const int2* __restrict__ epack,
                                                   const float* __restrict__ dinv,
                                                   const float* __restrict__ b2,
                                                   float* __restrict__ out) {
    int n = blockIdx.x * 4 + (threadIdx.x >> 6);
    int l = threadIdx.x & 63;
    if (n >= N_NODES) return;
    bool act = (l < 40);
    int ll = act ? l : l - 40;   // idle lanes mirror low features: loads stay in-row
    float di = dinv[n];
    float acc[8];
    acc[0] = di * di * HW[(size_t)n * 40 + ll];
    #pragma unroll
    for (int k = 1; k < 8; ++k) acc[k] = 0.f;
    int e0 = off[n], e1 = off[n + 1];
    for (int base = e0; base < e1; base += 8) {
        int last = e1 - 1;
        int2 p[8];
        float w[8];
        #pragma unroll
        for (int k = 0; k < 8; ++k) {
            int e = base + k;
            int idx = min(e, last);
            p[k] = epack[idx];
            w[k] = (e < e1) ? __int_as_float(p[k].y) : 0.f;
        }
        #pragma unroll
        for (int k = 0; k < 8; ++k) {
            float g = HW[(size_t)p[k].x * 40 + ll];
            acc[k] += w[k] * g;
        }
    }
    float a = ((acc[0] + acc[1]) + (acc[2] + acc[3])) + ((acc[4] + acc[5]) + (acc[6] + acc[7]));
    a += b2[ll];
    float m = act ? a : -1e30f;
    #pragma unroll
    for (int d = 32; d; d >>= 1) m = fmaxf(m, __shfl_xor(m, d, 64));
    float pexp = act ? expf(a - m) : 0.f;
    float s = pexp;
    #pragma unroll
    for (int d = 32; d; d >>= 1) s += __shfl_xor(s, d, 64);
    if (act) out[(size_t)n * 40 + l] = pexp / s;
}

// ---------------- launch ----------------

extern "C" void kernel_launch(void* const* d_in, const int* in_sizes, int n_in,
                              void* d_out, int out_size, void* d_ws, size_t ws_size,
                              hipStream_t stream) {
    const float* x  = (const float*)d_in[0];
    const int*   ei = (const int*)d_in[1];
    const float* ew = (const float*)d_in[2];
    // d_in[3] = attention (PERIODS=1 -> softmax = 1.0, unused)
    const float* W1 = (const float*)d_in[4];
    const float* b1 = (const float*)d_in[5];
    const float* W2 = (const float*)d_in[6];
    const float* b2 = (const float*)d_in[7];
    float* out = (float*)d_out;

    char* p = (char*)d_ws;
    auto alloc = [&](size_t bytes) -> void* {
        void* r = (void*)p;
        p += (bytes + 511) & ~(size_t)511;
        return r;
    };
    unsigned long long* packed = (unsigned long long*)alloc((size_t)N_NODES * 8);
    float* dinv   = (float*)alloc((size_t)N_NODES * 4);
    int*   off    = (int*)alloc((size_t)(N_NODES + 1) * 4);
    int*   bsum   = (int*)alloc(1024 * 4);
    int*   seq    = (int*)alloc((size_t)N_EDGES * 4);
    int2*  epack  = (int2*)alloc((size_t)N_EDGES * 8);
    float* XW     = (float*)alloc((size_t)N_NODES * 128 * 4);
    float* HW     = (float*)alloc((size_t)N_NODES * 40 * 4);

    int nblk_n = (N_NODES + 255) / 256;
    int nblk_e = (N_EDGES + 255) / 256;
    int nblk_s = (N_NODES + 1023) / 1024;   // 98

    hipLaunchKernelGGL(init_kernel,  dim3(nblk_n), dim3(256), 0, stream, packed);
    hipLaunchKernelGGL(count_kernel, dim3(nblk_e), dim3(256), 0, stream, ei, ew, packed, seq);
    hipLaunchKernelGGL(scanA_kernel, dim3(nblk_s), dim3(1024), 0, stream, packed, off, bsum, dinv);
    hipLaunchKernelGGL(scanB_kernel, dim3(1), dim3(1024), 0, stream, bsum, nblk_s);
    hipLaunchKernelGGL(scanC_kernel, dim3(nblk_s), dim3(1024), 0, stream, off, bsum);
    hipLaunchKernelGGL(fill_kernel,  dim3(nblk_e), dim3(256), 0, stream, ei, ew, dinv, off, seq, epack);

    hipLaunchKernelGGL(gemm1_kernel, dim3((N_NODES + 127) / 128), dim3(256), 0, stream, x, W1, XW);
    hipLaunchKernelGGL(agg1f_kernel, dim3(N_NODES / 4), dim3(256), 0, stream,
                       XW, off, epack, dinv, b1, W2, HW);
    hipLaunchKernelGGL(agg2_kernel,  dim3((N_NODES + 3) / 4), dim3(256), 0, stream,
                       HW, off, epack, dinv, b2, out);
}